// Round 10
// baseline (235.519 us; speedup 1.0000x reference)
//
#include <hip/hip_runtime.h>

#define T_STEPS 2000
#define BATCH   2048

// Pin a uniform value into a VGPR once (preamble only — in-loop ties regressed
// in round 6). With constants in VGPRs, each step fma carries at most ONE
// SGPR operand (u or c from v_readlane), so no v_mov broadcasts in the loop.
#define FORCE_VGPR(x) asm("" : "+v"(x))

// Fully fused conv + recurrence, rotating-ring wave per batch element.
// Ring invariant (entering step t): lane L holds
//   R_L = cba + sum_{tau<=t-1} (a[63-(t+L-tau)]/mc)*c_tau + gamma-weighted f's
// Per step t:
//   1. R += af * c_t        (af[L]=a[63-L]/mc; lane 0 becomes u_t)
//   2. u = readlane(R,0); q = med3(poly(u), 0, 5)    (relu + clamp)
//   3. f = M*q*(135135+17325w+378w^2+w^3)/(135135+62370w+3150w^2+28w^3), w=q^2
//      (Pade[7/6] tanh — verified round 9, absmax 0.5; one v_rcp, no exp2)
//   4. rotate R down one lane (DPP wave_rol:1), lane 63 <- cba (fresh slot)
//   5. R += gam * f         (gam[L]=(1000/mc)*b_lag[63-L], fixed per lane)
//   6. F = cndmask(rotl1(F), f, lane63)              (output collector)
// 23 VALU/step, no LDS/scratch/tables in the hot loop.
__global__ __launch_bounds__(256) void fused_kernel(
    const float* __restrict__ currents, const float* __restrict__ a,
    const float* __restrict__ b_lag, const float* __restrict__ poly_coeff,
    const float* __restrict__ b_act, const float* __restrict__ max_current,
    const float* __restrict__ max_firing_rate, float* __restrict__ out)
{
    int tid  = threadIdx.x;
    int lane = tid & 63;
    int wid  = tid >> 6;
    int b    = blockIdx.x * 4 + wid;

    float inv = 1.0f / max_current[0];
    float cba = -b_act[0] * inv;
    float af  = a[63 - lane] * inv;                 // per-lane conv tap (VGPR)
    float gam = (1000.0f * inv) * b_lag[63 - lane]; // per-lane feedback tap (VGPR)

    // inner polynomial p = k0 + k1 u + k2 u^2 + k3 u^3 (squared coeffs)
    float c0 = poly_coeff[0], c1 = poly_coeff[1], c2 = poly_coeff[2], c3 = poly_coeff[3];
    float k0 = c0 * c0, k1 = c1 * c1, k2 = c2 * c2, k3 = c3 * c3;
    float M  = max_firing_rate[0];
    // Pade[7/6] tanh, M folded into numerator
    float N0 = 135135.0f * M, N1 = 17325.0f * M, N2 = 378.0f * M;
    float D0 = 135135.0f, D1 = 62370.0f, D2 = 3150.0f, D3 = 28.0f;
    float C5 = 5.0f;

    // one-time VGPR pinning (14 uniforms) — keeps every loop fma <= 1 SGPR src
    FORCE_VGPR(cba);
    FORCE_VGPR(k0); FORCE_VGPR(k1); FORCE_VGPR(k2); FORCE_VGPR(k3);
    FORCE_VGPR(M);  FORCE_VGPR(N0); FORCE_VGPR(N1); FORCE_VGPR(N2);
    FORCE_VGPR(D0); FORCE_VGPR(D1); FORCE_VGPR(D2); FORCE_VGPR(D3);
    FORCE_VGPR(C5);

    auto bcast = [](float v, int l) {
        return __builtin_bit_cast(float,
            __builtin_amdgcn_readlane(__builtin_bit_cast(int, v), l));
    };
    auto rotl1 = [](float v) {   // dst[L] = src[(L+1) & 63]
        int i = __builtin_bit_cast(int, v);
        return __builtin_bit_cast(float,
            __builtin_amdgcn_update_dpp(i, i, 0x134, 0xf, 0xf, false));
    };

    const float* ccol   = currents + b;
    float*       outcol = out + b;

    bool  is63 = (lane == 63);               // loop-invariant cndmask predicate
    float R  = cba;                          // all slots born with the bias
    float F  = 0.0f;                         // output collector
    float cv = ccol[(long)lane * BATCH];     // currents c[lane] for chunk 0

    auto step = [&](int s) {
        float c = bcast(cv, s);                        // c_t -> SGPR (1 SGPR src ok)
        R = fmaf(af, c, R);                            // complete lane 0 -> u_t
        float u = bcast(R, 0);                         // u_t -> SGPR
        float u2 = u * u;                              // same SGPR twice: legal
        float a1 = fmaf(u, k1, k0);                    // u SGPR + 2 VGPR consts
        float a2 = fmaf(u, k3, k2);
        float p  = fmaf(u2, a2, a1);
        float q  = __builtin_amdgcn_fmed3f(p, 0.0f, C5);   // relu + clamp
        float w  = q * q;
        float N  = fmaf(w, fmaf(w, fmaf(w, M,  N2), N1), N0);
        float D  = fmaf(w, fmaf(w, fmaf(w, D3, D2), D1), D0);
        float r  = __builtin_amdgcn_rcpf(D);
        float f  = (q * N) * r;                        // M*tanh(q) >= 0
        float Rr = rotl1(R);                           // slots shift down one lane
        Rr = is63 ? cba : Rr;                          // fresh slot for t+64
        R  = fmaf(gam, f, Rr);
        float Fr = rotl1(F);                           // collect f in rotating reg
        F  = is63 ? f : Fr;
        (void)s;
    };

    // 31 full chunks of 64 steps (t = 0 .. 1983)
    for (int chunk = 0; chunk < 31; ++chunk) {
        long t0 = (long)chunk * 64;
        long tp = t0 + 64 + lane;                      // prefetch next currents
        float cvn = (tp < T_STEPS) ? ccol[tp * BATCH] : 0.0f;
#pragma unroll
        for (int s = 0; s < 64; ++s) step(s);
        outcol[(t0 + lane) * BATCH] = F;               // lane L = f[t0+L]
        cv = cvn;
    }
    // tail: 16 steps (t = 1984 .. 1999); f[1984+s] ends at lane 48+s
#pragma unroll
    for (int s = 0; s < 16; ++s) step(s);
    if (lane >= 48) outcol[(long)(1984 + lane - 48) * BATCH] = F;
}

extern "C" void kernel_launch(void* const* d_in, const int* in_sizes, int n_in,
                              void* d_out, int out_size, void* d_ws, size_t ws_size,
                              hipStream_t stream) {
    const float* currents   = (const float*)d_in[0];
    const float* a          = (const float*)d_in[1];
    const float* b_lag      = (const float*)d_in[2];
    const float* poly_coeff = (const float*)d_in[3];
    const float* b_act      = (const float*)d_in[4];
    const float* mc         = (const float*)d_in[5];
    const float* mfr        = (const float*)d_in[6];
    float* out = (float*)d_out;

    fused_kernel<<<BATCH / 4, 256, 0, stream>>>(
        currents, a, b_lag, poly_coeff, b_act, mc, mfr, out);
}